// Round 1
// baseline (155.466 us; speedup 1.0000x reference)
//
#include <hip/hip_runtime.h>
#include <math.h>

// Problem constants: N=128, LQ=LK=64, D=512, H=8 (head split is a no-op in the einsum).
#define DN 512          // feature dim
#define NROWS 8192      // N * LQ = 128*64 rows of Q/K
#define NB 128          // batch N

typedef unsigned short ushort_t;
typedef __attribute__((ext_vector_type(8))) short bf16x8;
typedef __attribute__((ext_vector_type(4))) float f32x4;

static __device__ __forceinline__ ushort_t f2bf(float f){
  unsigned u = __float_as_uint(f);
  u += 0x7fffu + ((u >> 16) & 1u);   // round-to-nearest-even
  return (ushort_t)(u >> 16);
}

// async global->LDS, 16B per lane; LDS dest is wave-uniform base + lane*16
#define GLL16(gp, lp)                                                          \
  __builtin_amdgcn_global_load_lds(                                            \
      (const __attribute__((address_space(1))) void*)(gp),                     \
      (__attribute__((address_space(3))) void*)(lp), 16, 0, 0)

// ---------------------------------------------------------------------------
// Convert a 512x512 fp32 weight matrix to bf16 (raw ushort bits).
__global__ __launch_bounds__(256) void convw_kernel(const float* __restrict__ W,
                                                    ushort_t* __restrict__ Wb) {
  int i = (blockIdx.x * 256 + threadIdx.x) * 4;
  float4 v = *(const float4*)&W[i];
  ushort4 h;
  h.x = f2bf(v.x); h.y = f2bf(v.y); h.z = f2bf(v.z); h.w = f2bf(v.w);
  *(ushort4*)&Wb[i] = h;
}

// ---------------------------------------------------------------------------
// Projection: Out[M=8192][512] (bf16) = X(fp32)[8192][512] @ Wb^T + bias.
// 128x128 tile, BK=64, 4 waves each computing a 64x64 quadrant via 16x16x32 MFMA.
__global__ __launch_bounds__(256) void proj_kernel(const float* __restrict__ X,
                                                   const ushort_t* __restrict__ Wb,
                                                   const float* __restrict__ bias,
                                                   ushort_t* __restrict__ Out) {
  __shared__ __align__(16) ushort_t As[128 * 64];
  __shared__ __align__(16) ushort_t Bs[128 * 64];
  const int tid = threadIdx.x;
  const int wave = tid >> 6, lane = tid & 63;
  const int wr = wave >> 1, wc = wave & 1;
  const int m0 = blockIdx.y * 128, n0 = blockIdx.x * 128;
  const int arow = lane & 15, kcol = (lane >> 4) * 8;

  f32x4 acc[4][4] = {};

  for (int kt = 0; kt < 8; ++kt) {
    const int k0 = kt * 64;
    // stage A: fp32 -> bf16, reg-staged (128 rows x 64 cols)
#pragma unroll
    for (int i = 0; i < 8; i++) {
      int e = i * 1024 + tid * 4;
      int r = e >> 6, c = e & 63;
      float4 v = *(const float4*)&X[(size_t)(m0 + r) * DN + k0 + c];
      ushort4 h;
      h.x = f2bf(v.x); h.y = f2bf(v.y); h.z = f2bf(v.z); h.w = f2bf(v.w);
      *(ushort4*)&As[r * 64 + c] = h;
    }
    // stage B: bf16 weights via async global->LDS (8 rows per instr per wave)
#pragma unroll
    for (int i = 0; i < 4; i++) {
      int r0 = wave * 32 + i * 8;
      GLL16(Wb + (size_t)(n0 + r0 + (lane >> 3)) * DN + k0 + (lane & 7) * 8,
            &Bs[r0 * 64]);
    }
    __syncthreads();

    bf16x8 af[4][2], bfr[4][2];
#pragma unroll
    for (int mi = 0; mi < 4; mi++)
#pragma unroll
      for (int ks = 0; ks < 2; ks++)
        af[mi][ks] = *(const bf16x8*)&As[(wr * 64 + mi * 16 + arow) * 64 + ks * 32 + kcol];
#pragma unroll
    for (int ni = 0; ni < 4; ni++)
#pragma unroll
      for (int ks = 0; ks < 2; ks++)
        bfr[ni][ks] = *(const bf16x8*)&Bs[(wc * 64 + ni * 16 + arow) * 64 + ks * 32 + kcol];
#pragma unroll
    for (int ks = 0; ks < 2; ks++)
#pragma unroll
      for (int mi = 0; mi < 4; mi++)
#pragma unroll
        for (int ni = 0; ni < 4; ni++)
          acc[mi][ni] = __builtin_amdgcn_mfma_f32_16x16x32_bf16(
              af[mi][ks], bfr[ni][ks], acc[mi][ni], 0, 0, 0);
    __syncthreads();
  }

  // epilogue: + bias, store bf16
  float bc[4];
#pragma unroll
  for (int ni = 0; ni < 4; ni++) bc[ni] = bias[n0 + wc * 64 + ni * 16 + arow];
#pragma unroll
  for (int mi = 0; mi < 4; mi++)
#pragma unroll
    for (int ni = 0; ni < 4; ni++)
#pragma unroll
      for (int j = 0; j < 4; j++) {
        int row = m0 + wr * 64 + mi * 16 + (lane >> 4) * 4 + j;
        int col = n0 + wc * 64 + ni * 16 + arow;
        Out[(size_t)row * DN + col] = f2bf(acc[mi][ni][j] + bc[ni]);
      }
}

// ---------------------------------------------------------------------------
// Pairwise logits + fused max/sum reductions.
// Grid (64,64): block tile = 128x128 of the 8192x8192 logits matrix = 2 a's x 2 b's.
// Each wave owns one (a,b) pair's 64x64 tile; K-loop over 512 in steps of 64.
__global__ __launch_bounds__(256) void pairs_kernel(const ushort_t* __restrict__ Q,
                                                    const ushort_t* __restrict__ Km,
                                                    const float* __restrict__ amask,
                                                    const float* __restrict__ ls_ptr,
                                                    float* __restrict__ out) {
  __shared__ __align__(16) ushort_t As[128 * 64];
  __shared__ __align__(16) ushort_t Bs[128 * 64];
  const int tid = threadIdx.x;
  const int wave = tid >> 6, lane = tid & 63;
  const int wr = wave >> 1, wc = wave & 1;
  const int by = blockIdx.y, bx = blockIdx.x;
  const int arow = lane & 15, kcol = (lane >> 4) * 8;

  f32x4 acc[4][4] = {};

  for (int kt = 0; kt < 8; ++kt) {
    const int k0 = kt * 64;
#pragma unroll
    for (int i = 0; i < 4; i++) {
      int r0 = wave * 32 + i * 8;
      GLL16(Q  + (size_t)(by * 128 + r0 + (lane >> 3)) * DN + k0 + (lane & 7) * 8,
            &As[r0 * 64]);
      GLL16(Km + (size_t)(bx * 128 + r0 + (lane >> 3)) * DN + k0 + (lane & 7) * 8,
            &Bs[r0 * 64]);
    }
    __syncthreads();

    bf16x8 af[4][2], bfr[4][2];
#pragma unroll
    for (int mi = 0; mi < 4; mi++)
#pragma unroll
      for (int ks = 0; ks < 2; ks++)
        af[mi][ks] = *(const bf16x8*)&As[(wr * 64 + mi * 16 + arow) * 64 + ks * 32 + kcol];
#pragma unroll
    for (int ni = 0; ni < 4; ni++)
#pragma unroll
      for (int ks = 0; ks < 2; ks++)
        bfr[ni][ks] = *(const bf16x8*)&Bs[(wc * 64 + ni * 16 + arow) * 64 + ks * 32 + kcol];
#pragma unroll
    for (int ks = 0; ks < 2; ks++)
#pragma unroll
      for (int mi = 0; mi < 4; mi++)
#pragma unroll
        for (int ni = 0; ni < 4; ni++)
          acc[mi][ni] = __builtin_amdgcn_mfma_f32_16x16x32_bf16(
              af[mi][ks], bfr[ni][ks], acc[mi][ni], 0, 0, 0);
    __syncthreads();
  }

  // ---- fused epilogue: per-pair reductions over the 64x64 tile ----
  // C/D layout (verified m89): col = lane&15, row = (lane>>4)*4 + reg.

  // t2v: per-row max over 64 cols, then sum over 64 rows
  float t2v = 0.f;
#pragma unroll
  for (int mi = 0; mi < 4; mi++) {
    f32x4 rm = acc[mi][0];
#pragma unroll
    for (int ni = 1; ni < 4; ni++)
#pragma unroll
      for (int j = 0; j < 4; j++) rm[j] = fmaxf(rm[j], acc[mi][ni][j]);
#pragma unroll
    for (int off = 1; off < 16; off <<= 1)
#pragma unroll
      for (int j = 0; j < 4; j++) rm[j] = fmaxf(rm[j], __shfl_xor(rm[j], off));
    t2v += rm[0] + rm[1] + rm[2] + rm[3];
  }
  t2v += __shfl_xor(t2v, 16);
  t2v += __shfl_xor(t2v, 32);

  // v2t: per-col max over 64 rows, then sum over 64 cols
  float v2t = 0.f;
#pragma unroll
  for (int ni = 0; ni < 4; ni++) {
    float cm = -INFINITY;
#pragma unroll
    for (int mi = 0; mi < 4; mi++)
#pragma unroll
      for (int j = 0; j < 4; j++) cm = fmaxf(cm, acc[mi][ni][j]);
    cm = fmaxf(cm, __shfl_xor(cm, 16));
    cm = fmaxf(cm, __shfl_xor(cm, 32));
    v2t += cm;
  }
#pragma unroll
  for (int off = 1; off < 16; off <<= 1) v2t += __shfl_xor(v2t, off);

  const int a = by * 2 + wr, b = bx * 2 + wc;
  // com_mask_sum[a] = sum of attention_mask[a, 0..63]
  float am = amask[a * 64 + lane];
#pragma unroll
  for (int off = 1; off < 64; off <<= 1) am += __shfl_xor(am, off);

  float ls = expf(ls_ptr[0]);
  float r = ls * 0.5f * (t2v / am + v2t / 64.0f);
  if (lane == 0) {
    out[a * NB + b] = r;                 // r
    out[NB * NB + b * NB + a] = r;       // r.T
  }
}

// ---------------------------------------------------------------------------
extern "C" void kernel_launch(void* const* d_in, const int* in_sizes, int n_in,
                              void* d_out, int out_size, void* d_ws, size_t ws_size,
                              hipStream_t stream) {
  const float* query = (const float*)d_in[0];
  const float* key   = (const float*)d_in[1];
  const float* amask = (const float*)d_in[2];
  const float* Wq    = (const float*)d_in[3];
  const float* bq    = (const float*)d_in[4];
  const float* Wk    = (const float*)d_in[5];
  const float* bk    = (const float*)d_in[6];
  const float* ls    = (const float*)d_in[7];

  char* ws = (char*)d_ws;
  ushort_t* WqB = (ushort_t*)(ws);                                 // 512 KB
  ushort_t* WkB = (ushort_t*)(ws + 512 * 1024);                    // 512 KB
  ushort_t* Qb  = (ushort_t*)(ws + 1024 * 1024);                   // 8 MB
  ushort_t* Kb  = (ushort_t*)(ws + 1024 * 1024 + 8 * 1024 * 1024); // 8 MB

  convw_kernel<<<256, 256, 0, stream>>>(Wq, WqB);
  convw_kernel<<<256, 256, 0, stream>>>(Wk, WkB);
  proj_kernel<<<dim3(4, 64), 256, 0, stream>>>(query, WqB, bq, Qb);
  proj_kernel<<<dim3(4, 64), 256, 0, stream>>>(key, WkB, bk, Kb);
  pairs_kernel<<<dim3(64, 64), 256, 0, stream>>>(Qb, Kb, amask, ls, (float*)d_out);
}

// Round 2
// 112.023 us; speedup vs baseline: 1.3878x; 1.3878x over previous
//
#include <hip/hip_runtime.h>
#include <math.h>

// Problem constants: N=128, LQ=LK=64, D=512, H=8 (head split is a no-op in the einsum).
#define DN 512          // feature dim
#define NB 128          // batch N

typedef unsigned short ushort_t;
typedef __attribute__((ext_vector_type(8))) short bf16x8;
typedef __attribute__((ext_vector_type(4))) float f32x4;

static __device__ __forceinline__ ushort_t f2bf(float f){
  unsigned u = __float_as_uint(f);
  u += 0x7fffu + ((u >> 16) & 1u);   // round-to-nearest-even
  return (ushort_t)(u >> 16);
}

// async global->LDS, 16B per lane; LDS dest is wave-uniform base + lane*16
#define GLL16(gp, lp)                                                          \
  __builtin_amdgcn_global_load_lds(                                            \
      (const __attribute__((address_space(1))) void*)(gp),                     \
      (__attribute__((address_space(3))) void*)(lp), 16, 0, 0)

#define BAR() __builtin_amdgcn_s_barrier()
#define LGKM0()                                                                \
  do {                                                                         \
    asm volatile("s_waitcnt lgkmcnt(0)" ::: "memory");                         \
    __builtin_amdgcn_sched_barrier(0);                                         \
  } while (0)
#define VMC(N)                                                                 \
  do {                                                                         \
    asm volatile("s_waitcnt vmcnt(" #N ")" ::: "memory");                      \
  } while (0)

// ---------------------------------------------------------------------------
// Projection: Out[M=8192][512] (bf16) = X(fp32)[8192][512] @ W^T + bias.
// 128x128 tile, BK=64, 4 waves, fp32 weights converted in-register while staging.
// LDS tiles use 16B-slot XOR swizzle (slot ^= row&7) on both write and read.
__global__ __launch_bounds__(256) void proj_kernel(const float* __restrict__ X,
                                                   const float* __restrict__ W,
                                                   const float* __restrict__ bias,
                                                   ushort_t* __restrict__ Out) {
  __shared__ __align__(16) ushort_t As[128 * 64];
  __shared__ __align__(16) ushort_t Bs[128 * 64];
  const int tid = threadIdx.x;
  const int wave = tid >> 6, lane = tid & 63;
  const int wr = wave >> 1, wc = wave & 1;
  const int m0 = blockIdx.y * 128, n0 = blockIdx.x * 128;
  const int arow = lane & 15, g = lane >> 4;

  f32x4 acc[4][4] = {};

  for (int kt = 0; kt < 8; ++kt) {
    const int k0 = kt * 64;
#pragma unroll
    for (int i = 0; i < 8; i++) {
      int e = i * 1024 + tid * 4;
      int r = e >> 6, c = e & 63;
      int cs = ((((c >> 3) ^ (r & 7)) << 3) | (c & 7));
      float4 va = *(const float4*)&X[(size_t)(m0 + r) * DN + k0 + c];
      ushort4 ha;
      ha.x = f2bf(va.x); ha.y = f2bf(va.y); ha.z = f2bf(va.z); ha.w = f2bf(va.w);
      *(ushort4*)&As[r * 64 + cs] = ha;
      float4 vb = *(const float4*)&W[(size_t)(n0 + r) * DN + k0 + c];
      ushort4 hb;
      hb.x = f2bf(vb.x); hb.y = f2bf(vb.y); hb.z = f2bf(vb.z); hb.w = f2bf(vb.w);
      *(ushort4*)&Bs[r * 64 + cs] = hb;
    }
    __syncthreads();

    bf16x8 af[4][2], bfr[4][2];
#pragma unroll
    for (int mi = 0; mi < 4; mi++)
#pragma unroll
      for (int ks = 0; ks < 2; ks++)
        af[mi][ks] = *(const bf16x8*)&As[(wr * 64 + mi * 16 + arow) * 64 +
                                         ((((ks << 2) | g) ^ (arow & 7)) << 3)];
#pragma unroll
    for (int ni = 0; ni < 4; ni++)
#pragma unroll
      for (int ks = 0; ks < 2; ks++)
        bfr[ni][ks] = *(const bf16x8*)&Bs[(wc * 64 + ni * 16 + arow) * 64 +
                                          ((((ks << 2) | g) ^ (arow & 7)) << 3)];
#pragma unroll
    for (int ks = 0; ks < 2; ks++)
#pragma unroll
      for (int mi = 0; mi < 4; mi++)
#pragma unroll
        for (int ni = 0; ni < 4; ni++)
          acc[mi][ni] = __builtin_amdgcn_mfma_f32_16x16x32_bf16(
              af[mi][ks], bfr[ni][ks], acc[mi][ni], 0, 0, 0);
    __syncthreads();
  }

  float bc[4];
#pragma unroll
  for (int ni = 0; ni < 4; ni++) bc[ni] = bias[n0 + wc * 64 + ni * 16 + arow];
#pragma unroll
  for (int mi = 0; mi < 4; mi++)
#pragma unroll
    for (int ni = 0; ni < 4; ni++)
#pragma unroll
      for (int j = 0; j < 4; j++) {
        int row = m0 + wr * 64 + mi * 16 + (lane >> 4) * 4 + j;
        int col = n0 + wc * 64 + ni * 16 + arow;
        Out[(size_t)row * DN + col] = f2bf(acc[mi][ni][j] + bc[ni]);
      }
}

// ---------------------------------------------------------------------------
// Pairwise logits + fused max/sum reductions. 256x256 tile of the 8192x8192
// logits (4 a's x 4 b's), 8 waves (2M x 4N), 8-phase double-buffered K-loop.
// Half-tile H_{4k+j}: j=0 A rows0-127, j=1 A rows128-255, j=2 B low, j=3 B high;
// K-tile k -> LDS buffer k&1. Stage lead = 5 half-tiles; vmcnt(2) at K-tile
// boundaries (vmcnt(0) entering the last tile).
__global__ __launch_bounds__(512, 2) void pairs_kernel(const ushort_t* __restrict__ Q,
                                                       const ushort_t* __restrict__ Km,
                                                       const float* __restrict__ amask,
                                                       const float* __restrict__ ls_ptr,
                                                       float* __restrict__ out) {
  __shared__ __align__(16) ushort_t lds[2 * 2 * 256 * 64];  // 128 KiB
  const int tid = threadIdx.x;
  const int wave = tid >> 6, lane = tid & 63;
  const int wr = wave >> 2, wc = wave & 3;      // 2M x 4N wave grid
  const int arow = lane & 15, g = lane >> 4;
  const int bid = blockIdx.x;
  const int bx = bid & 31, by = bid >> 5;
  const int l8 = lane >> 3, l7 = lane & 7;
  const int srcSlot = l7 ^ l8;                  // pre-swizzled global source slot

  f32x4 acc[8][4] = {};
  bf16x8 aR[4][2], bR[4][2];

  // stage half-tile ht (2 x global_load_lds per thread; 512 thr * 32B = 16 KiB)
  auto STG = [&](int ht) {
    if (ht > 31) return;
    const int k = ht >> 2, j = ht & 3, d = k & 1, op = j >> 1, half = j & 1;
    const ushort_t* src = op ? Km : Q;
    const int tb = (op ? bx : by) * 256;
#pragma unroll
    for (int i = 0; i < 2; i++) {
      int ldsRow = half * 128 + wave * 16 + i * 8;           // wave-uniform
      GLL16(src + (size_t)(tb + ldsRow + l8) * DN + k * 64 + srcSlot * 8,
            &lds[((d * 2 + op) * 256 + ldsRow) * 64]);
    }
  };
  auto LDA = [&](int mh, int d) {
#pragma unroll
    for (int mi = 0; mi < 4; mi++)
#pragma unroll
      for (int ks = 0; ks < 2; ks++) {
        int row = wr * 128 + (mh * 4 + mi) * 16 + arow;
        int slot = ((ks << 2) | g) ^ (arow & 7);
        aR[mi][ks] = *(const bf16x8*)&lds[((d * 2 + 0) * 256 + row) * 64 + slot * 8];
      }
  };
  auto LDB = [&](int nh, int d) {
#pragma unroll
    for (int ni = 0; ni < 2; ni++)
#pragma unroll
      for (int ks = 0; ks < 2; ks++) {
        int row = wc * 64 + (nh * 2 + ni) * 16 + arow;
        int slot = ((ks << 2) | g) ^ (arow & 7);
        bR[nh * 2 + ni][ks] = *(const bf16x8*)&lds[((d * 2 + 1) * 256 + row) * 64 + slot * 8];
      }
  };
  auto MMA = [&](int mh, int nh) {
    __builtin_amdgcn_s_setprio(1);
#pragma unroll
    for (int ks = 0; ks < 2; ks++)
#pragma unroll
      for (int mi = 0; mi < 4; mi++)
#pragma unroll
        for (int ni = 0; ni < 2; ni++)
          acc[mh * 4 + mi][nh * 2 + ni] = __builtin_amdgcn_mfma_f32_16x16x32_bf16(
              aR[mi][ks], bR[nh * 2 + ni][ks], acc[mh * 4 + mi][nh * 2 + ni], 0, 0, 0);
    __builtin_amdgcn_s_setprio(0);
  };

  // prologue: stage H0..H4, wait for H0..H3 (H4 stays in flight)
  STG(0); STG(1); STG(2); STG(3); STG(4);
  VMC(2);
  BAR();

#pragma unroll
  for (int t = 0; t < 4; ++t) {
#pragma unroll
    for (int kk = 0; kk < 2; ++kk) {
      const int k = t * 2 + kk, d = k & 1;
      const int P = k * 4;
      // q0: A-low frags + B-left frags
      LDA(0, d); LDB(0, d);
      STG(P + 0 + 5);
      BAR(); LGKM0();
      MMA(0, 0);
      BAR();
      // q1: B-right frags
      LDB(1, d);
      STG(P + 1 + 5);
      BAR(); LGKM0();
      MMA(0, 1);
      BAR();
      // q2: A-high frags (A fully read after this phase's lgkm)
      LDA(1, d);
      STG(P + 2 + 5);
      BAR(); LGKM0();
      MMA(1, 0);
      BAR();
      // q3: no ds reads; counted-vmcnt boundary into K-tile k+1
      STG(P + 3 + 5);
      if (k < 7) {
        if (k == 6) { VMC(0); } else { VMC(2); }
      }
      BAR();
      MMA(1, 1);
      BAR();
    }
  }

  // ---- fused epilogue: two (a,b) pairs per wave ----
  // C/D layout: col = lane&15, row = (lane>>4)*4 + reg.
  const float lsv = expf(ls_ptr[0]);
#pragma unroll
  for (int ph = 0; ph < 2; ph++) {
    // t2v: per-row max over 64 cols, summed over 64 rows
    float t2v = 0.f;
#pragma unroll
    for (int mi = ph * 4; mi < ph * 4 + 4; mi++) {
      f32x4 rm = acc[mi][0];
#pragma unroll
      for (int ni = 1; ni < 4; ni++)
#pragma unroll
        for (int j = 0; j < 4; j++) rm[j] = fmaxf(rm[j], acc[mi][ni][j]);
#pragma unroll
      for (int off = 1; off < 16; off <<= 1)
#pragma unroll
        for (int j = 0; j < 4; j++) rm[j] = fmaxf(rm[j], __shfl_xor(rm[j], off));
      t2v += rm[0] + rm[1] + rm[2] + rm[3];
    }
    t2v += __shfl_xor(t2v, 16);
    t2v += __shfl_xor(t2v, 32);

    // v2t: per-col max over 64 rows, summed over 64 cols
    float v2t = 0.f;
#pragma unroll
    for (int ni = 0; ni < 4; ni++) {
      float cm = -INFINITY;
#pragma unroll
      for (int mi = ph * 4; mi < ph * 4 + 4; mi++)
#pragma unroll
        for (int j = 0; j < 4; j++) cm = fmaxf(cm, acc[mi][ni][j]);
      cm = fmaxf(cm, __shfl_xor(cm, 16));
      cm = fmaxf(cm, __shfl_xor(cm, 32));
      v2t += cm;
    }
#pragma unroll
    for (int off = 1; off < 16; off <<= 1) v2t += __shfl_xor(v2t, off);

    const int a = by * 4 + wr * 2 + ph, b = bx * 4 + wc;
    float am = amask[a * 64 + lane];
#pragma unroll
    for (int off = 1; off < 64; off <<= 1) am += __shfl_xor(am, off);

    float r = lsv * 0.5f * (t2v / am + v2t / 64.0f);
    if (lane == 0) {
      out[a * NB + b] = r;                 // r
      out[NB * NB + b * NB + a] = r;       // r.T
    }
  }
}

// ---------------------------------------------------------------------------
extern "C" void kernel_launch(void* const* d_in, const int* in_sizes, int n_in,
                              void* d_out, int out_size, void* d_ws, size_t ws_size,
                              hipStream_t stream) {
  const float* query = (const float*)d_in[0];
  const float* key   = (const float*)d_in[1];
  const float* amask = (const float*)d_in[2];
  const float* Wq    = (const float*)d_in[3];
  const float* bq    = (const float*)d_in[4];
  const float* Wk    = (const float*)d_in[5];
  const float* bk    = (const float*)d_in[6];
  const float* ls    = (const float*)d_in[7];

  char* ws = (char*)d_ws;
  ushort_t* Qb = (ushort_t*)(ws);                      // 8 MB
  ushort_t* Kb = (ushort_t*)(ws + 8 * 1024 * 1024);    // 8 MB

  proj_kernel<<<dim3(4, 64), 256, 0, stream>>>(query, Wq, bq, Qb);
  proj_kernel<<<dim3(4, 64), 256, 0, stream>>>(key, Wk, bk, Kb);
  pairs_kernel<<<dim3(1024), 512, 0, stream>>>(Qb, Kb, amask, ls, (float*)d_out);
}